// Round 6
// baseline (169.542 us; speedup 1.0000x reference)
//
#include <hip/hip_runtime.h>

// VQ-VAE VectorQuantizer forward, MI355X (gfx950), fp32.
// N=32768 points x D=64 dims, K=1024 codes.
// Out: [0]=loss, [1..QE]=quantized [B,D,H,W], [+..]=indices [B,H*W] as f32.
//
// R6: LDS-free distance loop. R2/R4/R5 all plateaued ~41-61 us of per-CU LDS
// instruction budget (every FMA operand streamed through the LDS pipe). Key
// asymmetry: e-rows are wave-uniform -> stream e via the SCALAR pipe (uniform
// restrict loads -> s_load; v_fmac with SGPR src0), keep x lane-private in 64
// VGPRs (1 point/lane). Main loop has ZERO LDS traffic; floor = FMA issue
// 65.5K cyc/SIMD ~ 27 us. K-split 8 across blocks (1024 blocks x 256 thr,
// 4 waves/SIMD), combine via packed (dist<<32|idx) u64 atomicMin (R5-proven;
// tie -> lower idx = np first-argmin; 0xAA poison = +inf). 64-deep dependent
// fmaf chain per (point,code) — bit-identical rounding to R1-R5 (absmax 0).

constexpr int D_   = 64;
constexpr int HW   = 1024;     // H*W
constexpr int K_   = 1024;
constexpr int CSL  = 128;      // codes per slice (K-split 8)
constexpr int PTS2 = 64;       // points per epilogue block
constexpr int SP   = 68;       // epilogue xT row stride
constexpr int QE   = 2097152;
constexpr int IDX_OFF = 1 + QE;

// ---- prologue: e2 (R1 expression) + zero loss accumulator / counter ----
__global__ void vq_e2_kernel(const float* __restrict__ emb,
                             float* __restrict__ e2,
                             float* __restrict__ loss_acc,
                             unsigned* __restrict__ cnt) {
  int k = blockIdx.x * 256 + threadIdx.x;
  if (k == 0) { loss_acc[0] = 0.0f; cnt[0] = 0u; }
  if (k >= K_) return;
  const float4* e4 = (const float4*)(emb + k * 64);
  float s = 0.f;
#pragma unroll
  for (int q = 0; q < 16; ++q) {
    float4 v = e4[q];
    s += v.x * v.x; s += v.y * v.y; s += v.z * v.z; s += v.w * v.w;
  }
  e2[k] = s;
}

// ---- distance + per-slice argmin: no LDS, no barriers ----
__global__ __launch_bounds__(256, 3) void vq_dist_kernel(
    const float* __restrict__ in, const float* __restrict__ emb,
    const float* __restrict__ e2g, unsigned long long* __restrict__ keys) {
  const int t     = threadIdx.x;
  const int blk   = blockIdx.x;        // 1024 = 128 ptiles x 8 slices
  const int ptile = blk >> 3;          // 256 points each
  const int kb    = (blk & 7) * CSL;
  const int b     = ptile >> 2;        // 4 ptiles per image
  const int hw    = (ptile & 3) * 256 + t;
  const float* xp = in + b * (D_ * HW) + hw;

  // lane-private point vector in VGPRs (coalesced dword loads, stride HW)
  float x[64];
#pragma unroll
  for (int d = 0; d < 64; ++d) x[d] = xp[d * HW];

  // x2: sequential-d fmaf chain — value-identical to R1's
  float x2 = 0.f;
#pragma unroll
  for (int d = 0; d < 64; ++d) x2 = fmaf(x[d], x[d], x2);

  float minv = 3.4e38f;
  int   mini = 0;

  // per code: 64 uniform e-loads (scalar pipe) feed 64 lane-private fmaf.
  // dot chain d-sequential; u = fl(fl(x2-2dot)+e2) — identical to R1-R5.
#pragma unroll 1
  for (int j = 0; j < CSL; ++j) {
    const float* __restrict__ er = emb + (kb + j) * 64;   // wave-uniform row
    float dot = 0.f;
#pragma unroll
    for (int d = 0; d < 64; ++d) dot = fmaf(x[d], er[d], dot);
    float u = fmaf(-2.f, dot, x2) + e2g[kb + j];
    if (u < minv) { minv = u; mini = kb + j; }   // strict <: first-min (k asc)
  }

  // dist > 0 -> IEEE order == unsigned order; low 32 = idx -> tie to lower idx
  unsigned long long key =
      (((unsigned long long)__float_as_uint(minv)) << 32) | (unsigned)mini;
  atomicMin(&keys[ptile * 256 + t], key);        // 0xAA.. poison acts as +inf
}

// ---- epilogue: gather, loss, straight-through quantized, indices ----
__global__ __launch_bounds__(256) void vq_epi_kernel(
    const float* __restrict__ in, const float* __restrict__ emb,
    const unsigned long long* __restrict__ keys, float* __restrict__ out,
    float* __restrict__ loss_acc, unsigned* __restrict__ cnt) {
  __shared__ float xT[D_ * SP];     // [d][p]; later holds ST values
  __shared__ int   idx_sel[PTS2];
  __shared__ float redbuf[4];

  const int t   = threadIdx.x;
  const int blk = blockIdx.x;       // 512 blocks, 64 points each
  const int b   = blk >> 4;         // 16 blocks per image
  const int hw0 = (blk & 15) * PTS2;
  const float* inb = in + b * (D_ * HW) + hw0;

#pragma unroll
  for (int i = 0; i < 4; ++i) {
    int fi = t + i * 256;                 // 0..1023 float4s
    int d = fi >> 4, p4 = fi & 15;
    *(float4*)(&xT[d * SP + p4 * 4]) = *(const float4*)(inb + d * HW + p4 * 4);
  }
  if (t < PTS2) {
    int ix = (int)(unsigned)(keys[blk * PTS2 + t] & 0xFFFFFFFFull);
    idx_sel[t] = ix;
    out[IDX_OFF + blk * PTS2 + t] = (float)ix;   // coalesced
  }
  __syncthreads();

  // gather codes, loss partial, overwrite xT with x + (q - x)  (R4/R5-proven)
  float lp = 0.f;
#pragma unroll
  for (int i = 0; i < 4; ++i) {
    int fi = t + i * 256;                 // 0..1023
    int p = fi & 63, qd = fi >> 6;        // p contiguous per wave
    int cidx = idx_sel[p];
    float4 q = *(const float4*)(emb + cidx * 64 + qd * 4);
    float xv0 = xT[(qd * 4 + 0) * SP + p];
    float xv1 = xT[(qd * 4 + 1) * SP + p];
    float xv2 = xT[(qd * 4 + 2) * SP + p];
    float xv3 = xT[(qd * 4 + 3) * SP + p];
    float d0 = q.x - xv0, d1 = q.y - xv1, d2 = q.z - xv2, d3 = q.w - xv3;
    lp = fmaf(d0, d0, lp); lp = fmaf(d1, d1, lp);
    lp = fmaf(d2, d2, lp); lp = fmaf(d3, d3, lp);
    xT[(qd * 4 + 0) * SP + p] = xv0 + d0;
    xT[(qd * 4 + 1) * SP + p] = xv1 + d1;
    xT[(qd * 4 + 2) * SP + p] = xv2 + d2;
    xT[(qd * 4 + 3) * SP + p] = xv3 + d3;
  }

  // loss: wave -> block -> one device atomic; last block finalizes out[0]
#pragma unroll
  for (int off = 1; off < 64; off <<= 1) lp += __shfl_xor(lp, off);
  if ((t & 63) == 0) redbuf[t >> 6] = lp;
  __syncthreads();   // also orders xT rewrites before the stores below
  if (t == 0) {
    atomicAdd(loss_acc, redbuf[0] + redbuf[1] + redbuf[2] + redbuf[3]);
    __threadfence();
    unsigned old = atomicAdd(cnt, 1u);
    if (old == 511u) {
      __threadfence();
      float total = atomicAdd(loss_acc, 0.0f);  // coherent read-back
      float m = total * (1.0f / 2097152.0f);
      out[0] = m + 0.25f * m;                   // ref op order
    }
  }

  // quantized output [B,D,H,W]: scalar coalesced stores (out+1 is 4B-aligned)
  float* outq = out + 1 + b * (D_ * HW) + hw0;
#pragma unroll
  for (int i = 0; i < 16; ++i) {
    int oi = t + i * 256;                 // 0..4095
    int d = oi >> 6, p = oi & 63;
    outq[d * HW + p] = xT[d * SP + p];
  }
}

extern "C" void kernel_launch(void* const* d_in, const int* in_sizes, int n_in,
                              void* d_out, int out_size, void* d_ws, size_t ws_size,
                              hipStream_t stream) {
  const float* in  = (const float*)d_in[0];
  const float* emb = (const float*)d_in[1];
  float* out = (float*)d_out;
  float*    loss_acc = (float*)d_ws;                                // ws[0]
  unsigned* cnt      = (unsigned*)d_ws + 4;                         // ws+16B
  float*    e2g      = (float*)((char*)d_ws + 256);                 // 4 KB
  unsigned long long* keys =
      (unsigned long long*)((char*)d_ws + 8192);                    // 256 KB

  // keys need NO init: 0xAA poison > any real key (dist>0 -> top bit 0)
  vq_e2_kernel<<<4, 256, 0, stream>>>(emb, e2g, loss_acc, cnt);
  vq_dist_kernel<<<1024, 256, 0, stream>>>(in, emb, e2g, keys);
  vq_epi_kernel<<<512, 256, 0, stream>>>(in, emb, keys, out, loss_acc, cnt);
}

// Round 7
// 169.504 us; speedup vs baseline: 1.0002x; 1.0002x over previous
//
#include <hip/hip_runtime.h>

// VQ-VAE VectorQuantizer forward, MI355X (gfx950), fp32.
// N=32768 points x D=64 dims, K=1024 codes.
// Out: [0]=loss, [1..QE]=quantized [B,D,H,W], [+..]=indices [B,H*W] as f32.
//
// R7: scalar-pipe e + register-tiled dots. R6 proved e scalarizes (SGPR=96,
// LDS=0) but holding x[64] live across the code loop made the compiler
// reload x per fmaf (VGPR=44 -> 8192 VMEM/lane). Interchange: d-outer,
// 16-code tile inner -> 16 per-lane dot accumulators (chains stay d-
// sequential = bit-identical rounding to R1-R6), one x dword + one
// s_load_dwordx16 (pre-transposed eT[d][k] in ws) + 16 v_fmac per d.
// VALU:VMEM=16:1, ~40 VGPR -> no pressure. Floor = FMA issue ~27 us.
// Combine via packed (dist<<32|idx) u64 atomicMin (tie -> lower idx = np
// first-argmin; 0xAA ws poison = +inf, keys need no init).

constexpr int D_   = 64;
constexpr int HW   = 1024;     // H*W
constexpr int CSL  = 128;      // codes per slice (K-split 8)
constexpr int PTS2 = 64;       // points per epilogue block
constexpr int SP   = 68;       // epilogue xT row stride
constexpr int QE   = 2097152;
constexpr int IDX_OFF = 1 + QE;

// ---- prep: transpose emb -> eT[64][1024], e2 (R1 expression), zero acc ----
__global__ __launch_bounds__(256) void vq_prep_kernel(
    const float* __restrict__ emb, float* __restrict__ eT,
    float* __restrict__ e2, float* __restrict__ loss_acc,
    unsigned* __restrict__ cnt) {
  __shared__ float tile[64 * 65];
  const int t  = threadIdx.x;
  const int k0 = blockIdx.x * 64;          // 16 blocks x 64 codes

  if (blockIdx.x == 0 && t == 0) { loss_acc[0] = 0.0f; cnt[0] = 0u; }

  // load 64 codes x 64 dims, coalesced float4
#pragma unroll
  for (int i = 0; i < 4; ++i) {
    int f = t + i * 256;                   // 0..1023 float4s
    int kl = f >> 4, d4 = f & 15;
    float4 v = *(const float4*)(emb + (k0 + kl) * 64 + d4 * 4);
    tile[kl * 65 + d4 * 4 + 0] = v.x;
    tile[kl * 65 + d4 * 4 + 1] = v.y;
    tile[kl * 65 + d4 * 4 + 2] = v.z;
    tile[kl * 65 + d4 * 4 + 3] = v.w;
  }
  __syncthreads();

  // store transposed, coalesced along k
#pragma unroll
  for (int i = 0; i < 16; ++i) {
    int f = t + i * 256;                   // 0..4095
    int d = f >> 6, kl = f & 63;
    eT[d * 1024 + k0 + kl] = tile[kl * 65 + d];
  }

  // e2 for this block's codes — expression identical to R1 (rounding!)
  if (t < 64) {
    const float4* e4 = (const float4*)(emb + (k0 + t) * 64);
    float s = 0.f;
#pragma unroll
    for (int q = 0; q < 16; ++q) {
      float4 v = e4[q];
      s += v.x * v.x; s += v.y * v.y; s += v.z * v.z; s += v.w * v.w;
    }
    e2[k0 + t] = s;
  }
}

// ---- distance + per-slice argmin: no LDS, no barriers, e via scalar pipe ----
__global__ __launch_bounds__(256, 4) void vq_dist_kernel(
    const float* __restrict__ in, const float* __restrict__ eTw,
    const float* __restrict__ e2g, unsigned long long* __restrict__ keys) {
  const int t     = threadIdx.x;
  const int blk   = blockIdx.x;        // 1024 = 128 ptiles x 8 slices
  const int ptile = blk >> 3;          // 256 points each
  const int kb    = (blk & 7) * CSL;
  const int b     = ptile >> 2;        // 4 ptiles per image
  const int hw    = (ptile & 3) * 256 + t;
  const float* xp = in + b * (D_ * HW) + hw;

  // x2: sequential-d fmaf chain — value-identical to R1-R6
  float x2 = 0.f;
#pragma unroll
  for (int d = 0; d < 64; ++d) { float xv = xp[d * HW]; x2 = fmaf(xv, xv, x2); }

  float minv = 3.4e38f;
  int   mini = 0;

  // 8 tiles of 16 codes; per d: 1 coalesced x dword (L1) + 1 s_load_dwordx16
  // (uniform eT row chunk) + 16 v_fmac. dot chains d-sequential (exact).
#pragma unroll 1
  for (int tl = 0; tl < 8; ++tl) {
    const float* __restrict__ et = eTw + kb + tl * 16;   // wave-uniform
    float dot[16];
#pragma unroll
    for (int j = 0; j < 16; ++j) dot[j] = 0.f;
#pragma unroll
    for (int d = 0; d < 64; ++d) {
      float xd = xp[d * HW];
#pragma unroll
      for (int j = 0; j < 16; ++j)
        dot[j] = fmaf(xd, et[d * 1024 + j], dot[j]);
    }
#pragma unroll
    for (int j = 0; j < 16; ++j) {
      float u = fmaf(-2.f, dot[j], x2) + e2g[kb + tl * 16 + j];  // R1 expr
      int cg = kb + tl * 16 + j;                                  // ascending
      if (u < minv) { minv = u; mini = cg; }   // strict <: first-min
    }
  }

  // dist > 0 -> IEEE order == unsigned order; low 32 = idx -> tie to lower idx
  unsigned long long key =
      (((unsigned long long)__float_as_uint(minv)) << 32) | (unsigned)mini;
  atomicMin(&keys[ptile * 256 + t], key);      // 0xAA.. poison acts as +inf
}

// ---- epilogue: gather, loss, straight-through quantized, indices ----
__global__ __launch_bounds__(256) void vq_epi_kernel(
    const float* __restrict__ in, const float* __restrict__ emb,
    const unsigned long long* __restrict__ keys, float* __restrict__ out,
    float* __restrict__ loss_acc, unsigned* __restrict__ cnt) {
  __shared__ float xT[D_ * SP];     // [d][p]; later holds ST values
  __shared__ int   idx_sel[PTS2];
  __shared__ float redbuf[4];

  const int t   = threadIdx.x;
  const int blk = blockIdx.x;       // 512 blocks, 64 points each
  const int b   = blk >> 4;         // 16 blocks per image
  const int hw0 = (blk & 15) * PTS2;
  const float* inb = in + b * (D_ * HW) + hw0;

#pragma unroll
  for (int i = 0; i < 4; ++i) {
    int fi = t + i * 256;                 // 0..1023 float4s
    int d = fi >> 4, p4 = fi & 15;
    *(float4*)(&xT[d * SP + p4 * 4]) = *(const float4*)(inb + d * HW + p4 * 4);
  }
  if (t < PTS2) {
    int ix = (int)(unsigned)(keys[blk * PTS2 + t] & 0xFFFFFFFFull);
    idx_sel[t] = ix;
    out[IDX_OFF + blk * PTS2 + t] = (float)ix;   // coalesced
  }
  __syncthreads();

  // gather codes, loss partial, overwrite xT with x + (q - x)  (R4-R6 proven)
  float lp = 0.f;
#pragma unroll
  for (int i = 0; i < 4; ++i) {
    int fi = t + i * 256;                 // 0..1023
    int p = fi & 63, qd = fi >> 6;        // p contiguous per wave
    int cidx = idx_sel[p];
    float4 q = *(const float4*)(emb + cidx * 64 + qd * 4);
    float xv0 = xT[(qd * 4 + 0) * SP + p];
    float xv1 = xT[(qd * 4 + 1) * SP + p];
    float xv2 = xT[(qd * 4 + 2) * SP + p];
    float xv3 = xT[(qd * 4 + 3) * SP + p];
    float d0 = q.x - xv0, d1 = q.y - xv1, d2 = q.z - xv2, d3 = q.w - xv3;
    lp = fmaf(d0, d0, lp); lp = fmaf(d1, d1, lp);
    lp = fmaf(d2, d2, lp); lp = fmaf(d3, d3, lp);
    xT[(qd * 4 + 0) * SP + p] = xv0 + d0;
    xT[(qd * 4 + 1) * SP + p] = xv1 + d1;
    xT[(qd * 4 + 2) * SP + p] = xv2 + d2;
    xT[(qd * 4 + 3) * SP + p] = xv3 + d3;
  }

  // loss: wave -> block -> one device atomic; last block finalizes out[0]
#pragma unroll
  for (int off = 1; off < 64; off <<= 1) lp += __shfl_xor(lp, off);
  if ((t & 63) == 0) redbuf[t >> 6] = lp;
  __syncthreads();   // also orders xT rewrites before the stores below
  if (t == 0) {
    atomicAdd(loss_acc, redbuf[0] + redbuf[1] + redbuf[2] + redbuf[3]);
    __threadfence();
    unsigned old = atomicAdd(cnt, 1u);
    if (old == 511u) {
      __threadfence();
      float total = atomicAdd(loss_acc, 0.0f);  // coherent read-back
      float m = total * (1.0f / 2097152.0f);
      out[0] = m + 0.25f * m;                   // ref op order
    }
  }

  // quantized output [B,D,H,W]: scalar coalesced stores (out+1 is 4B-aligned)
  float* outq = out + 1 + b * (D_ * HW) + hw0;
#pragma unroll
  for (int i = 0; i < 16; ++i) {
    int oi = t + i * 256;                 // 0..4095
    int d = oi >> 6, p = oi & 63;
    outq[d * HW + p] = xT[d * SP + p];
  }
}

extern "C" void kernel_launch(void* const* d_in, const int* in_sizes, int n_in,
                              void* d_out, int out_size, void* d_ws, size_t ws_size,
                              hipStream_t stream) {
  const float* in  = (const float*)d_in[0];
  const float* emb = (const float*)d_in[1];
  float* out = (float*)d_out;
  float*    loss_acc = (float*)d_ws;                                // ws[0]
  unsigned* cnt      = (unsigned*)d_ws + 4;                         // ws+16B
  float*    e2g      = (float*)((char*)d_ws + 256);                 // 4 KB
  float*    eT       = (float*)((char*)d_ws + 8192);                // 256 KB
  unsigned long long* keys =
      (unsigned long long*)((char*)d_ws + 8192 + 262144);           // 256 KB

  // keys need NO init: 0xAA poison > any real key (dist>0 -> top bit 0)
  vq_prep_kernel<<<16, 256, 0, stream>>>(emb, eT, e2g, loss_acc, cnt);
  vq_dist_kernel<<<1024, 256, 0, stream>>>(in, eT, e2g, keys);
  vq_epi_kernel<<<512, 256, 0, stream>>>(in, emb, keys, out, loss_acc, cnt);
}